// Round 1
// baseline (225.750 us; speedup 1.0000x reference)
//
#include <hip/hip_runtime.h>
#include <math.h>

// RoPE: x (8,16,4096,64) fp32, token_positions (8,16,4096) int.
// out[..., 2j]   = cos(p*f_j)*x[...,2j]   - sin(p*f_j)*x[...,2j+1]
// out[..., 2j+1] = sin(p*f_j)*x[...,2j]   + cos(p*f_j)*x[...,2j+1]
// f_j = theta^(-2j/64) = 2^(j * (-log2(theta)/32)), theta = 10000.
//
// One thread per float4 = 2 pairs. 8*16*4096 rows * 16 quads/row = 8,388,608
// threads = 32768 blocks x 256. Fully coalesced 16B/lane loads/stores.

#define N_ROWS   (8 * 16 * 4096)        // 524,288
#define QUADS    (N_ROWS * 16)          // 8,388,608 float4s

__global__ __launch_bounds__(256) void rope_kernel(
    const float* __restrict__ x,
    const int*   __restrict__ pos,
    float*       __restrict__ out)
{
    const unsigned idx  = blockIdx.x * 256u + threadIdx.x;  // float4 index
    const unsigned row  = idx >> 4;
    const unsigned quad = idx & 15u;

    const float p = (float)pos[row];

    // inv_freq for pair j: 2^(j * c), c = -log2(10000)/32
    const float c = -0.41524101186092029f;
    const float j0 = (float)(2u * quad);
    const float inv0 = exp2f(j0 * c);
    const float inv1 = exp2f((j0 + 1.0f) * c);

    float s0, c0, s1, c1;
    sincosf(p * inv0, &s0, &c0);
    sincosf(p * inv1, &s1, &c1);

    const float4 v = ((const float4*)x)[idx];
    float4 o;
    o.x = c0 * v.x - s0 * v.y;
    o.y = s0 * v.x + c0 * v.y;
    o.z = c1 * v.z - s1 * v.w;
    o.w = s1 * v.z + c1 * v.w;
    ((float4*)out)[idx] = o;
}

extern "C" void kernel_launch(void* const* d_in, const int* in_sizes, int n_in,
                              void* d_out, int out_size, void* d_ws, size_t ws_size,
                              hipStream_t stream) {
    const float* x   = (const float*)d_in[0];
    const int*   pos = (const int*)d_in[1];
    float*       out = (float*)d_out;

    const int block = 256;
    const int grid  = QUADS / block;  // exact: 32768
    rope_kernel<<<grid, block, 0, stream>>>(x, pos, out);
}

// Round 3
// 224.808 us; speedup vs baseline: 1.0042x; 1.0042x over previous
//
#include <hip/hip_runtime.h>
#include <math.h>

// RoPE: x (8,16,4096,64) fp32, token_positions (8,16,4096) int.
// out[..., 2j]   = cos(p*f_j)*x[...,2j] - sin(p*f_j)*x[...,2j+1]
// out[..., 2j+1] = sin(p*f_j)*x[...,2j] + cos(p*f_j)*x[...,2j+1]
// f_j = theta^(-2j/64), theta = 10000.
//
// One thread per float4 = 2 pairs; fully coalesced 16B/lane.
// Transcendentals on the HW pipe: v_exp_f32 / v_fract_f32 / v_sin_f32 /
// v_cos_f32 (sin/cos take REVOLUTIONS; fract keeps input in valid range).
// Work entirely in revolutions: inv_freq_rev_j = theta^(-2j/64) / (2*pi)
//   = 2^(j*c + d), c = -log2(10000)/32, d = -log2(2*pi).

#define N_ROWS   (8 * 16 * 4096)        // 524,288
#define QUADS    (N_ROWS * 16)          // 8,388,608 float4s

__global__ __launch_bounds__(256) void rope_kernel(
    const float* __restrict__ x,
    const int*   __restrict__ pos,
    float*       __restrict__ out)
{
    const unsigned idx  = blockIdx.x * 256u + threadIdx.x;  // float4 index
    const unsigned row  = idx >> 4;
    const unsigned quad = idx & 15u;

    const float p = (float)pos[row];

    // inv_freq (in revolutions) for pair j: 2^(j*c + d)
    const float c = -0.41524101186092029f;   // -log2(10000)/32
    const float d = -2.6514961294723187f;    // -log2(2*pi)
    const float j0 = (float)(2u * quad);
    const float inv0 = __builtin_amdgcn_exp2f(fmaf(j0, c, d));
    const float inv1 = __builtin_amdgcn_exp2f(fmaf(j0 + 1.0f, c, d));

    // angle in revolutions, reduced to [0,1) for the HW sin/cos pipe
    const float r0 = __builtin_amdgcn_fractf(p * inv0);
    const float r1 = __builtin_amdgcn_fractf(p * inv1);

    const float s0 = __builtin_amdgcn_sinf(r0);
    const float c0 = __builtin_amdgcn_cosf(r0);
    const float s1 = __builtin_amdgcn_sinf(r1);
    const float c1 = __builtin_amdgcn_cosf(r1);

    const float4 v = ((const float4*)x)[idx];
    float4 o;
    o.x = c0 * v.x - s0 * v.y;
    o.y = s0 * v.x + c0 * v.y;
    o.z = c1 * v.z - s1 * v.w;
    o.w = s1 * v.z + c1 * v.w;
    ((float4*)out)[idx] = o;
}

extern "C" void kernel_launch(void* const* d_in, const int* in_sizes, int n_in,
                              void* d_out, int out_size, void* d_ws, size_t ws_size,
                              hipStream_t stream) {
    const float* x   = (const float*)d_in[0];
    const int*   pos = (const int*)d_in[1];
    float*       out = (float*)d_out;

    const int block = 256;
    const int grid  = QUADS / block;  // exact: 32768
    rope_kernel<<<grid, block, 0, stream>>>(x, pos, out);
}

// Round 4
// 218.701 us; speedup vs baseline: 1.0322x; 1.0279x over previous
//
#include <hip/hip_runtime.h>
#include <math.h>

// RoPE: x (8,16,4096,64) fp32, token_positions (8,16,4096) int.
// out[..., 2j]   = cos(p*f_j)*x[...,2j] - sin(p*f_j)*x[...,2j+1]
// out[..., 2j+1] = sin(p*f_j)*x[...,2j] + cos(p*f_j)*x[...,2j+1]
// f_j = theta^(-2j/64), theta = 10000.
//
// R4: 4 float4s per thread (stride 256 float4s = wave-coalesced per access,
// 4 outstanding vmem loads for latency hiding), nontemporal load/store
// (pure streaming, no reuse). quad = idx & 15 is k-invariant, so inv_freq
// is computed once per thread. HW transcendental pipe (v_exp/v_fract/
// v_sin/v_cos, revolutions domain).

#define N_ROWS   (8 * 16 * 4096)        // 524,288
#define QUADS    (N_ROWS * 16)          // 8,388,608 float4s

typedef float v4f __attribute__((ext_vector_type(4)));

__global__ __launch_bounds__(256) void rope_kernel(
    const float* __restrict__ x,
    const int*   __restrict__ pos,
    float*       __restrict__ out)
{
    const unsigned base = blockIdx.x * 1024u + threadIdx.x;  // float4 idx, k=0
    const unsigned quad = base & 15u;  // invariant over k (stride 256 ≡ 0 mod 16)

    // inv_freq (in revolutions) for pair j: 2^(j*c + d)
    const float c = -0.41524101186092029f;   // -log2(10000)/32
    const float d = -2.6514961294723187f;    // -log2(2*pi)
    const float j0 = (float)(2u * quad);
    const float inv0 = __builtin_amdgcn_exp2f(fmaf(j0, c, d));
    const float inv1 = __builtin_amdgcn_exp2f(fmaf(j0 + 1.0f, c, d));

    float p[4];
    v4f   v[4];
#pragma unroll
    for (int k = 0; k < 4; ++k) {
        const unsigned idx = base + (unsigned)k * 256u;
        p[k] = (float)pos[idx >> 4];
        v[k] = __builtin_nontemporal_load((const v4f*)x + idx);
    }

#pragma unroll
    for (int k = 0; k < 4; ++k) {
        const unsigned idx = base + (unsigned)k * 256u;
        const float r0 = __builtin_amdgcn_fractf(p[k] * inv0);
        const float r1 = __builtin_amdgcn_fractf(p[k] * inv1);
        const float s0 = __builtin_amdgcn_sinf(r0);
        const float c0 = __builtin_amdgcn_cosf(r0);
        const float s1 = __builtin_amdgcn_sinf(r1);
        const float c1 = __builtin_amdgcn_cosf(r1);
        v4f o;
        o.x = c0 * v[k].x - s0 * v[k].y;
        o.y = s0 * v[k].x + c0 * v[k].y;
        o.z = c1 * v[k].z - s1 * v[k].w;
        o.w = s1 * v[k].z + c1 * v[k].w;
        __builtin_nontemporal_store(o, (v4f*)out + idx);
    }
}

extern "C" void kernel_launch(void* const* d_in, const int* in_sizes, int n_in,
                              void* d_out, int out_size, void* d_ws, size_t ws_size,
                              hipStream_t stream) {
    const float* x   = (const float*)d_in[0];
    const int*   pos = (const int*)d_in[1];
    float*       out = (float*)d_out;

    const int block = 256;
    const int grid  = QUADS / (block * 4);  // 8192 blocks, 4 float4s/thread
    rope_kernel<<<grid, block, 0, stream>>>(x, pos, out);
}